// Round 2
// baseline (458.597 us; speedup 1.0000x reference)
//
#include <hip/hip_runtime.h>

typedef unsigned short u16;
typedef float floatx4 __attribute__((ext_vector_type(4)));
typedef short shortx8 __attribute__((ext_vector_type(8)));

#define MFMA16(a, b, c) __builtin_amdgcn_mfma_f32_16x16x32_bf16(a, b, c, 0, 0, 0)

__device__ __forceinline__ u16 f2b(float f) {
    union { float f; unsigned u; } c;
    c.f = f;
    unsigned lsb = (c.u >> 16) & 1u;
    c.u += 0x7fffu + lsb;           // round-to-nearest-even
    return (u16)(c.u >> 16);
}

__global__ __launch_bounds__(256) void scatter_flags(const int* __restrict__ e,
                                                     unsigned char* __restrict__ fl,
                                                     int n) {
    int i = blockIdx.x * 256 + threadIdx.x;
    if (i < n) fl[e[i]] = 1;
}

// Convert weights fp32 [K][N] -> bf16 transposed [N][K] (B-fragment friendly).
__global__ __launch_bounds__(256) void prep_weights(
    const float* __restrict__ W1r, const float* __restrict__ W1o,
    const float* __restrict__ W2r, const float* __restrict__ W2o,
    u16* __restrict__ W1rt, u16* __restrict__ W1ot,
    u16* __restrict__ W2rt, u16* __restrict__ W2ot)
{
    int t = blockIdx.x * 256 + threadIdx.x;
    union { u16 h[4]; unsigned long long ll; } pk;
    if (t < 2048) {                       // W1r: [64][128] -> [128][64]
        int n = t >> 4, k0 = (t & 15) * 4;
        #pragma unroll
        for (int j = 0; j < 4; ++j) pk.h[j] = f2b(W1r[(k0 + j) * 128 + n]);
        *(unsigned long long*)(W1rt + n * 64 + k0) = pk.ll;
    } else if (t < 4096) {                // W1o
        int tt = t - 2048; int n = tt >> 4, k0 = (tt & 15) * 4;
        #pragma unroll
        for (int j = 0; j < 4; ++j) pk.h[j] = f2b(W1o[(k0 + j) * 128 + n]);
        *(unsigned long long*)(W1ot + n * 64 + k0) = pk.ll;
    } else if (t < 8192) {                // W2r: [128][128] -> [128][128]
        int tt = t - 4096; int n = tt >> 5, k0 = (tt & 31) * 4;
        #pragma unroll
        for (int j = 0; j < 4; ++j) pk.h[j] = f2b(W2r[(k0 + j) * 128 + n]);
        *(unsigned long long*)(W2rt + n * 128 + k0) = pk.ll;
    } else if (t < 12288) {               // W2o
        int tt = t - 8192; int n = tt >> 5, k0 = (tt & 31) * 4;
        #pragma unroll
        for (int j = 0; j < 4; ++j) pk.h[j] = f2b(W2o[(k0 + j) * 128 + n]);
        *(unsigned long long*)(W2ot + n * 128 + k0) = pk.ll;
    }
}

// One block = 4 graphs (64 rows), 4 waves. Wave w owns output cols [2w*16, (2w+2)*16).
// Transposed dataflow (all layouts derived from the verified 16x16x32 fragment maps):
//   y1  = MFMA(ax, b1r)   C-layout [node: q*4+r][f: lr]  == zero-padded-K16 A-frag of y1^T
//   y2t = MFMA(b1o, ax)   C-layout [f: q*4+r][node: lr]  (operand-swap = transpose)
//   agg^T = MFMA16(pad(y1), pad(wbar^T), C=y2t(+bias))   -> h^T: 4 consecutive f/lane
//   -> one b64 store into s_h[node][f]; layer 2 identical; out -> float4 stores.
// The K16 aggregation uses ONLY the verified K32 instruction: both operands carry
// data in k_phys = q*8+{0..3} (logical k16 = q*4+{0..3}), zeros in q*8+{4..7}.
// 2 barriers per block; no s_t scratch. LDS = 27904 B (padded rows, 4-bank
// rotation per row exactly as the verified baseline) -> 5 blocks/CU.
__global__ __launch_bounds__(256, 5) void sage_mfma(
    const float* __restrict__ x,               // [B*16, 64] f32
    const unsigned char* __restrict__ flags,   // [B*16]
    const float* __restrict__ adjp,            // [16,16] f32
    const float* __restrict__ br1,             // [128] f32
    const float* __restrict__ br2,             // [128] f32
    const u16* __restrict__ W1rt,              // [128][64] bf16 (transposed)
    const u16* __restrict__ W1ot,              // [128][64]
    const u16* __restrict__ W2rt,              // [128][128]
    const u16* __restrict__ W2ot,              // [128][128]
    float* __restrict__ out)                   // [B*16,128] f32
{
    __shared__ __align__(16) unsigned char smem[27904];
    u16*   s_x   = (u16*)smem;                  // [64][72] bf16 padded (9216 B)
    u16*   s_h   = (u16*)(smem + 9216);         // [64][136] bf16 padded (17408 B)
    float* s_adj = (float*)(smem + 26624);      // [16][16] f32 (1024 B)
    float* s_flag= (float*)(smem + 27648);      // [64] f32 (256 B)

    const int b   = blockIdx.x;
    const int tid = threadIdx.x;
    const int w   = tid >> 6;
    const int l   = tid & 63;
    const int q   = l >> 4;
    const int lr  = l & 15;
    const int tn0 = 2 * w;
    const floatx4 fz = {0.f, 0.f, 0.f, 0.f};

    // ---- stage x (f32 -> bf16, padded rows), flags, adjp --------------------
    {
        const float4* xg = (const float4*)(x + (size_t)b * 4096);
        #pragma unroll
        for (int i = 0; i < 4; ++i) {
            int e = tid + i * 256;
            float4 v = xg[e];
            int row = e >> 4, f = (e & 15) * 4;
            union { u16 h[4]; unsigned long long ll; } pk;
            pk.h[0] = f2b(v.x); pk.h[1] = f2b(v.y); pk.h[2] = f2b(v.z); pk.h[3] = f2b(v.w);
            *(unsigned long long*)(s_x + row * 72 + f) = pk.ll;
        }
    }
    if (tid < 64) s_flag[tid] = flags[b * 64 + tid] ? 1.0f : 0.0f;
    s_adj[tid] = adjp[tid];
    __syncthreads();                                        // barrier 1 of 2

    // ---- per-lane wbar^T fragments, zero-padded-K16 B layout ----------------
    // lane(q,lr) elem jj<4 = wbar[i=lr][j=q*4+jj]; elems 4..7 = 0.
    shortx8 wb8[4];
    #pragma unroll
    for (int g = 0; g < 4; ++g) {
        float s = 0.f;
        #pragma unroll
        for (int j = 0; j < 16; ++j) s += s_adj[lr * 16 + j] * s_flag[g * 16 + j];
        float fi = s_flag[g * 16 + lr];
        float ti = fi / fmaxf(s * fi, 1.0f);                // flag_i / max(deg_i, 1)
        #pragma unroll
        for (int jj = 0; jj < 4; ++jj) {
            int j = q * 4 + jj;
            wb8[g][jj] = (short)f2b(ti * s_flag[g * 16 + j] * s_adj[lr * 16 + j]);
            wb8[g][jj + 4] = 0;
        }
    }

    // ---- layer-1 weight fragments + biases (L2-hot) -------------------------
    shortx8 b1r[2][2], b1o[2][2];
    floatx4 bias1[2], bias2[2];
    #pragma unroll
    for (int tni = 0; tni < 2; ++tni) {
        int n0 = (tn0 + tni) * 16;
        bias1[tni] = *(const floatx4*)(br1 + n0 + q * 4);
        bias2[tni] = *(const floatx4*)(br2 + n0 + q * 4);
        int n = n0 + lr;
        #pragma unroll
        for (int ks = 0; ks < 2; ++ks) {
            b1r[tni][ks] = *(const shortx8*)(W1rt + n * 64 + ks * 32 + q * 8);
            b1o[tni][ks] = *(const shortx8*)(W1ot + n * 64 + ks * 32 + q * 8);
        }
    }

    // ---- Phase A+B fused: h^T = relu(wbar@(x@W1r) + x@W1o + b1) -> s_h ------
    #pragma unroll
    for (int tm = 0; tm < 4; ++tm) {
        shortx8 ax[2];
        #pragma unroll
        for (int ks = 0; ks < 2; ++ks)
            ax[ks] = *(const shortx8*)(s_x + (tm * 16 + lr) * 72 + ks * 32 + q * 8);
        #pragma unroll
        for (int tni = 0; tni < 2; ++tni) {
            floatx4 y1 = fz, y2t = bias1[tni];
            #pragma unroll
            for (int ks = 0; ks < 2; ++ks) {
                y1  = MFMA16(ax[ks], b1r[tni][ks], y1);     // [node][f]
                y2t = MFMA16(b1o[tni][ks], ax[ks], y2t);    // [f][node] (+bias)
            }
            shortx8 a1 = {(short)f2b(y1[0]), (short)f2b(y1[1]),
                          (short)f2b(y1[2]), (short)f2b(y1[3]), 0, 0, 0, 0};
            floatx4 ag = MFMA16(a1, wb8[tm], y2t);          // agg^T + y2^T + b1
            union { u16 h[4]; unsigned long long ll; } pk;
            #pragma unroll
            for (int r = 0; r < 4; ++r) pk.h[r] = f2b(fmaxf(ag[r], 0.f));
            *(unsigned long long*)(s_h + (tm * 16 + lr) * 136 +
                                   (tn0 + tni) * 16 + q * 4) = pk.ll;
        }
    }
    __syncthreads();                                        // barrier 2 of 2

    // ---- Phase C+D fused: out = wbar@(h@W2r) + h@W2o + b2 -------------------
    #pragma unroll
    for (int tni = 0; tni < 2; ++tni) {
        int n = (tn0 + tni) * 16 + lr;
        shortx8 b2r[4], b2o[4];
        #pragma unroll
        for (int ks = 0; ks < 4; ++ks) {
            b2r[ks] = *(const shortx8*)(W2rt + n * 128 + ks * 32 + q * 8);
            b2o[ks] = *(const shortx8*)(W2ot + n * 128 + ks * 32 + q * 8);
        }
        #pragma unroll
        for (int tm = 0; tm < 4; ++tm) {
            floatx4 u1 = fz, u2t = bias2[tni];
            #pragma unroll
            for (int ks = 0; ks < 4; ++ks) {
                shortx8 ah = *(const shortx8*)(s_h + (tm * 16 + lr) * 136 +
                                               ks * 32 + q * 8);
                u1  = MFMA16(ah, b2r[ks], u1);              // [node][fo]
                u2t = MFMA16(b2o[ks], ah, u2t);             // [fo][node] (+bias)
            }
            shortx8 a2 = {(short)f2b(u1[0]), (short)f2b(u1[1]),
                          (short)f2b(u1[2]), (short)f2b(u1[3]), 0, 0, 0, 0};
            floatx4 og = MFMA16(a2, wb8[tm], u2t);          // final tile, transposed
            *(floatx4*)(out + ((size_t)b * 64 + tm * 16 + lr) * 128 +
                        (tn0 + tni) * 16 + q * 4) = og;     // 4 consecutive fo
        }
    }
}

extern "C" void kernel_launch(void* const* d_in, const int* in_sizes, int n_in,
                              void* d_out, int out_size, void* d_ws, size_t ws_size,
                              hipStream_t stream) {
    const float* x    = (const float*)d_in[0];
    const int*   edge = (const int*)d_in[1];
    const float* adjp = (const float*)d_in[2];
    const float* W1r  = (const float*)d_in[3];
    const float* br1  = (const float*)d_in[4];
    const float* W1o  = (const float*)d_in[5];
    const float* W2r  = (const float*)d_in[6];
    const float* br2  = (const float*)d_in[7];
    const float* W2o  = (const float*)d_in[8];
    float* out = (float*)d_out;

    const int total_nodes = in_sizes[0] / 64;      // 524288
    const int nedge       = in_sizes[1];           // 262144
    const int nblocks     = total_nodes / 64;      // 8192

    unsigned char* flags = (unsigned char*)d_ws;
    u16* wbase = (u16*)((char*)d_ws + 524288);
    u16* W1rt = wbase;            // 8192 u16
    u16* W1ot = wbase + 8192;
    u16* W2rt = wbase + 16384;    // 16384 u16
    u16* W2ot = wbase + 32768;

    hipMemsetAsync(flags, 0, (size_t)total_nodes, stream);
    scatter_flags<<<(nedge + 255) / 256, 256, 0, stream>>>(edge, flags, nedge);
    prep_weights<<<48, 256, 0, stream>>>(W1r, W1o, W2r, W2o, W1rt, W1ot, W2rt, W2ot);
    sage_mfma<<<nblocks, 256, 0, stream>>>(x, flags, adjp, br1, br2,
                                           W1rt, W1ot, W2rt, W2ot, out);
}